// Round 4
// baseline (426.310 us; speedup 1.0000x reference)
//
#include <hip/hip_runtime.h>
#include <math.h>

#define VOCAB   100000
#define EMBED   300
#define HIDDEN  300
#define BATCH   32768
#define K_NEG   10
#define EPSV    1e-5f

#define KPAD      320        // K padded to multiple of 32 (bf16 MFMA K)
#define NPAD      384        // weight rows padded to 3*128 N tiles
#define CV_STRIDE 304        // center_v bf16 row stride in shorts (608 B)
#define CTX8_STRIDE 304      // fp8 ctx row stride in BYTES (19 lanes * 16 B)
#define FP8_SCALE 64.0f      // power of 2 -> exact descale
#define FP8_DESCALE 0.015625f
#define NBUCKET 512

typedef __attribute__((ext_vector_type(8))) short  short8;
typedef __attribute__((ext_vector_type(4))) float  f32x4;
typedef __attribute__((ext_vector_type(2))) float  floatx2;

#if defined(__has_builtin)
#if __has_builtin(__builtin_amdgcn_cvt_pk_f32_fp8) && __has_builtin(__builtin_amdgcn_cvt_pk_fp8_f32)
#define HAVE_CVT_FP8 1
#endif
#endif

__device__ inline float b2f(unsigned short u) {
    union { unsigned int i; float f; } v; v.i = ((unsigned int)u) << 16; return v.f;
}
__device__ inline unsigned short f2b(float f) {
    union { float f; unsigned int i; } v; v.f = f;
    unsigned int r = v.i + 0x7FFFu + ((v.i >> 16) & 1u);   // RNE
    return (unsigned short)(r >> 16);
}
__device__ inline void up2(unsigned int u, float& lo, float& hi) {
    union { unsigned int i; float f; } a, b;
    a.i = u << 16; b.i = u & 0xFFFF0000u;
    lo = a.f; hi = b.f;
}
__device__ inline float wave_red(float v) {
    #pragma unroll
    for (int o = 32; o; o >>= 1) v += __shfl_down(v, o);
    return v;
}
__device__ inline float softplusf(float x) {
    return x > 0.f ? x + log1pf(expf(-x)) : log1pf(expf(x));
}

// ---- fp8 e4m3 helpers (hardware cvt when available, manual fallback) ------
__device__ inline float fp8_to_f(unsigned int u8) {
    const unsigned s = (u8 >> 7) & 1, e = (u8 >> 3) & 15, m = u8 & 7;
    float v;
    if (e) { union { unsigned i; float f; } b; b.i = ((e + 120u) << 23) | (m << 20); v = b.f; }
    else v = (float)m * 0.001953125f;
    return s ? -v : v;
}
__device__ inline unsigned char f_to_fp8(float x) {
    union { float f; unsigned i; } b; b.f = x;
    const unsigned s = (b.i >> 31) << 7;
    const float a = fabsf(x);
    if (a >= 440.f) return (unsigned char)(s | 0x7E);
    if (a < 0.015625f) {
        int m = (int)rintf(a * 512.f);
        return (unsigned char)(m >= 8 ? (s | 0x08) : (s | (unsigned)m));
    }
    unsigned r = (b.i & 0x7FFFFFFFu) + 0x7FFFFu + ((b.i >> 20) & 1u);
    unsigned e8 = (r >> 23) - 120u;
    unsigned m8 = (r >> 20) & 7u;
    if (e8 > 15u) return (unsigned char)(s | 0x7E);
    return (unsigned char)(s | (e8 << 3) | m8);
}
__device__ inline unsigned enc4fp8(float a, float b, float c, float d) {
#ifdef HAVE_CVT_FP8
    int v = 0;
    v = __builtin_amdgcn_cvt_pk_fp8_f32(a, b, v, false);
    v = __builtin_amdgcn_cvt_pk_fp8_f32(c, d, v, true);
    return (unsigned)v;
#else
    return (unsigned)f_to_fp8(a) | ((unsigned)f_to_fp8(b) << 8) |
           ((unsigned)f_to_fp8(c) << 16) | ((unsigned)f_to_fp8(d) << 24);
#endif
}
__device__ inline void dec4fp8(unsigned u, float* f) {
#ifdef HAVE_CVT_FP8
    floatx2 lo = __builtin_amdgcn_cvt_pk_f32_fp8((int)u, false);
    floatx2 hi = __builtin_amdgcn_cvt_pk_f32_fp8((int)u, true);
    f[0] = lo[0]; f[1] = lo[1]; f[2] = hi[0]; f[3] = hi[1];
#else
    f[0] = fp8_to_f(u); f[1] = fp8_to_f(u >> 8);
    f[2] = fp8_to_f(u >> 16); f[3] = fp8_to_f(u >> 24);
#endif
}

__device__ inline void load_lds16(const void* g, void* l) {
    __builtin_amdgcn_global_load_lds(
        (const __attribute__((address_space(1))) unsigned int*)g,
        (__attribute__((address_space(3))) unsigned int*)l, 16, 0, 0);
}

// ---------------------------------------------------------------------------
// prep: pack W_enc/W_dec -> bf16 [NPAD][KPAD]; gather+pack center rows ->
// bf16 [BATCH][KPAD]; pack context_emb -> fp8 e4m3 (x64) [VOCAB][304 B].
// ---------------------------------------------------------------------------
#define NW (2 * NPAD * 40)
#define NE (BATCH * 40)
#define NC (VOCAB * 19)

__global__ __launch_bounds__(256)
void prep_kernel(const float* __restrict__ W_enc, const float* __restrict__ W_dec,
                 const float* __restrict__ cemb, const int* __restrict__ cids,
                 const float* __restrict__ xemb,
                 unsigned short* __restrict__ wenc_b, unsigned short* __restrict__ wdec_b,
                 unsigned short* __restrict__ emb_b, unsigned char* __restrict__ ctx8)
{
    const int gid = blockIdx.x * 256 + threadIdx.x;
    if (gid < NW) {
        const int mat = gid / (NPAD * 40);
        const int rem = gid - mat * (NPAD * 40);
        const int r   = rem / 40;
        const int c8  = (rem - r * 40) * 8;
        const float* src = mat ? W_dec : W_enc;
        unsigned short* dst = mat ? wdec_b : wenc_b;
        unsigned short t[8];
        #pragma unroll
        for (int j = 0; j < 8; ++j) {
            const int c = c8 + j;
            t[j] = (r < 300 && c < 300) ? f2b(src[r * 300 + c]) : (unsigned short)0;
        }
        *(uint4*)(dst + (size_t)r * KPAD + c8) = *(const uint4*)t;
    } else if (gid < NW + NE) {
        const int g2  = gid - NW;
        const int row = g2 / 40;
        const int c8  = (g2 - row * 40) * 8;
        const float* src = cemb + (size_t)cids[row] * 300;
        unsigned short t[8];
        if (c8 + 7 < 300) {
            float4 a = *(const float4*)(src + c8);
            float4 b = *(const float4*)(src + c8 + 4);
            t[0]=f2b(a.x); t[1]=f2b(a.y); t[2]=f2b(a.z); t[3]=f2b(a.w);
            t[4]=f2b(b.x); t[5]=f2b(b.y); t[6]=f2b(b.z); t[7]=f2b(b.w);
        } else {
            #pragma unroll
            for (int j = 0; j < 8; ++j) {
                const int c = c8 + j;
                t[j] = (c < 300) ? f2b(src[c]) : (unsigned short)0;
            }
        }
        *(uint4*)(emb_b + (size_t)row * KPAD + c8) = *(const uint4*)t;
    } else if (gid < NW + NE + NC) {
        const int g3  = gid - (NW + NE);
        const int row = g3 / 19;
        const int l   = g3 - row * 19;
        const int e0  = l * 16;
        const float* src = xemb + (size_t)row * 300 + e0;
        float v[16];
        #pragma unroll
        for (int q = 0; q < 4; ++q) {
            if (e0 + q * 4 + 3 < 300) {
                float4 a = *(const float4*)(src + q * 4);
                v[q*4+0]=a.x; v[q*4+1]=a.y; v[q*4+2]=a.z; v[q*4+3]=a.w;
            } else {
                #pragma unroll
                for (int j = 0; j < 4; ++j) {
                    const int e = e0 + q * 4 + j;
                    v[q*4+j] = (e < 300) ? src[q*4+j] : 0.f;
                }
            }
        }
        unsigned u[4];
        #pragma unroll
        for (int q = 0; q < 4; ++q)
            u[q] = enc4fp8(v[q*4]*FP8_SCALE, v[q*4+1]*FP8_SCALE,
                           v[q*4+2]*FP8_SCALE, v[q*4+3]*FP8_SCALE);
        *(uint4*)(ctx8 + (size_t)row * CTX8_STRIDE + e0) = make_uint4(u[0],u[1],u[2],u[3]);
    }
}

// ---------------------------------------------------------------------------
// MFMA bf16 GEMM with global_load_lds staging + permuted LDS layout.
// C[m,n] = sum_k A[m,k]*B[n,k] + bias[n];  A:[BATCH][KPAD], B:[NPAD][KPAD]
// LDS tile: 128 rows x 64 B (4 col16 groups), col group stored at
// perm(c,r) = (c + r + (r>>2)) & 3  -> conflict-free ds_read_b128 frags
// while keeping the DMA's lane-contiguous LDS write.
// ---------------------------------------------------------------------------
template <int OSTRIDE, bool PAD_ZERO>
__global__ __launch_bounds__(256)
void mfma_gemm_kernel(const unsigned short* __restrict__ A,
                      const unsigned short* __restrict__ B,
                      const float* __restrict__ bias,
                      unsigned short* __restrict__ C)
{
    __shared__ unsigned short As[128 * 32];
    __shared__ unsigned short Bs[128 * 32];

    const int tid  = threadIdx.x;
    const int wave = tid >> 6;
    const int lane = tid & 63;
    const int m0 = blockIdx.y * 128;
    const int n0 = blockIdx.x * 128;

    const int wr = (wave & 1) * 64;
    const int wc = (wave >> 1) * 64;
    const int fr = lane & 15;
    const int fq = lane >> 4;

    // --- staging descriptors: instr t covers rows [16t,16t+16), wave w owns
    // t in {2w, 2w+1}; lane l -> row 16t+(l>>2), lds col16 l&3, global col16
    // c = ((l&3) - r - (r>>2)) & 3.
    const unsigned short* gA[2];
    const unsigned short* gB[2];
    int ldsOff[2];
    #pragma unroll
    for (int inst = 0; inst < 2; ++inst) {
        const int t = wave * 2 + inst;
        const int r = (t << 4) + (lane >> 2);
        const int c = ((lane & 3) - r - (r >> 2)) & 3;
        gA[inst] = A + (size_t)(m0 + r) * KPAD + c * 8;
        gB[inst] = B + (size_t)(n0 + r) * KPAD + c * 8;
        ldsOff[inst] = t << 9;              // shorts (1024 B per instr)
    }

    // --- fragment LDS offsets (loop-invariant)
    int aoff[4], boff[4];
    #pragma unroll
    for (int i = 0; i < 4; ++i) {
        const int ra = wr + i * 16 + fr;
        aoff[i] = (ra << 5) + (((fq + ra + (ra >> 2)) & 3) << 3);
        const int rb = wc + i * 16 + fr;
        boff[i] = (rb << 5) + (((fq + rb + (rb >> 2)) & 3) << 3);
    }

    f32x4 acc[4][4] = {};

    for (int k0 = 0; k0 < KPAD; k0 += 32) {
        #pragma unroll
        for (int inst = 0; inst < 2; ++inst) {
            load_lds16(gA[inst] + k0, As + ldsOff[inst]);
            load_lds16(gB[inst] + k0, Bs + ldsOff[inst]);
        }
        __syncthreads();                    // drains vmcnt -> LDS tile ready

        short8 af[4], bf[4];
        #pragma unroll
        for (int i = 0; i < 4; ++i) af[i] = *(const short8*)&As[aoff[i]];
        #pragma unroll
        for (int j = 0; j < 4; ++j) bf[j] = *(const short8*)&Bs[boff[j]];
        __syncthreads();                    // all waves done reading tile

        #pragma unroll
        for (int i = 0; i < 4; ++i)
            #pragma unroll
            for (int j = 0; j < 4; ++j)
                acc[i][j] = __builtin_amdgcn_mfma_f32_16x16x32_bf16(
                    af[i], bf[j], acc[i][j], 0, 0, 0);
    }

    #pragma unroll
    for (int i = 0; i < 4; ++i) {
        #pragma unroll
        for (int r = 0; r < 4; ++r) {
            const int m = m0 + wr + i * 16 + fq * 4 + r;
            unsigned short* crow = C + (size_t)m * OSTRIDE;
            #pragma unroll
            for (int j = 0; j < 4; ++j) {
                const int n = n0 + wc + j * 16 + fr;
                if (n < 300) {
                    crow[n] = f2b(acc[i][j][r] + bias[n]);
                } else if (PAD_ZERO && n < OSTRIDE) {
                    crow[n] = 0;
                }
            }
        }
    }
}

// ---------------------------------------------------------------------------
// score + CE: one block per batch row; waves 0-2 = score groups
// {pos,n0,n1,n2} {n3..n6} {n7..n9}, wave 3 = cross-entropy.
// ---------------------------------------------------------------------------
__global__ __launch_bounds__(256)
void score_ce_kernel(const unsigned short* __restrict__ cvb,
                     const unsigned short* __restrict__ encb,
                     const unsigned char* __restrict__ ctx8,
                     const int* __restrict__ ctx_ids, const int* __restrict__ neg_ids,
                     const int* __restrict__ labels,
                     const float* __restrict__ W_cls, const float* __restrict__ b_cls,
                     float* __restrict__ db, float* __restrict__ cb)
{
    const int g    = threadIdx.x >> 6;   // wave id = unit
    const int lane = threadIdx.x & 63;
    const int row  = blockIdx.x;
    const bool act = lane < 19;          // 19 lanes * 16 elements = 304

    __shared__ float blk[2];
    if (threadIdx.x < 2) blk[threadIdx.x] = 0.f;
    __syncthreads();

    const uint4 Z4 = make_uint4(0, 0, 0, 0);

    if (g < 3) {
        // ------- skip-gram scores -------
        int ids[4]; int nsc; bool hasPos = false;
        const int b = row * K_NEG;
        if (g == 0) {
            hasPos = true; nsc = 4;
            ids[0] = ctx_ids[row];
            ids[1] = neg_ids[b+0]; ids[2] = neg_ids[b+1]; ids[3] = neg_ids[b+2];
        } else if (g == 1) {
            nsc = 4;
            ids[0] = neg_ids[b+3]; ids[1] = neg_ids[b+4];
            ids[2] = neg_ids[b+5]; ids[3] = neg_ids[b+6];
        } else {
            nsc = 3;
            ids[0] = neg_ids[b+7]; ids[1] = neg_ids[b+8];
            ids[2] = neg_ids[b+9]; ids[3] = neg_ids[b+9];
        }

        const char* cvp = (const char*)(cvb + (size_t)row * CV_STRIDE);
        uint4 c0 = act ? *(const uint4*)(cvp + lane * 32)      : Z4;
        uint4 c1 = act ? *(const uint4*)(cvp + lane * 32 + 16) : Z4;

        uint4 gv[4];
        #pragma unroll
        for (int j = 0; j < 4; ++j)
            gv[j] = act ? *(const uint4*)(ctx8 + (size_t)ids[j] * CTX8_STRIDE + lane * 16)
                        : Z4;

        float cvf[16];
        up2(c0.x, cvf[0], cvf[1]);  up2(c0.y, cvf[2], cvf[3]);
        up2(c0.z, cvf[4], cvf[5]);  up2(c0.w, cvf[6], cvf[7]);
        up2(c1.x, cvf[8], cvf[9]);  up2(c1.y, cvf[10], cvf[11]);
        up2(c1.z, cvf[12], cvf[13]);up2(c1.w, cvf[14], cvf[15]);

        float ds[4];
        #pragma unroll
        for (int j = 0; j < 4; ++j) {
            float gf[16];
            dec4fp8(gv[j].x, gf); dec4fp8(gv[j].y, gf + 4);
            dec4fp8(gv[j].z, gf + 8); dec4fp8(gv[j].w, gf + 12);
            float s = 0.f;
            #pragma unroll
            for (int e = 0; e < 16; ++e) s = fmaf(cvf[e], gf[e], s);
            ds[j] = s;
        }
        #pragma unroll
        for (int j = 0; j < 4; ++j) ds[j] = wave_red(ds[j]);

        if (lane == 0) {
            float local = 0.f;
            #pragma unroll
            for (int j = 0; j < 4; ++j) {
                if (j < nsc) {
                    float s = fminf(10.f, fmaxf(-10.f, ds[j] * FP8_DESCALE));
                    local += softplusf((hasPos && j == 0) ? -s : s);
                }
            }
            atomicAdd(&blk[0], local);
        }
    } else {
        // ------- cross entropy -------
        const char* evp = (const char*)(encb + (size_t)row * KPAD);
        uint4 e0 = act ? *(const uint4*)(evp + lane * 32)      : Z4;
        uint4 e1 = act ? *(const uint4*)(evp + lane * 32 + 16) : Z4;
        float ev[16];
        up2(e0.x, ev[0], ev[1]);  up2(e0.y, ev[2], ev[3]);
        up2(e0.z, ev[4], ev[5]);  up2(e0.w, ev[6], ev[7]);
        up2(e1.x, ev[8], ev[9]);  up2(e1.y, ev[10], ev[11]);
        up2(e1.z, ev[12], ev[13]);up2(e1.w, ev[14], ev[15]);

        float p0 = 0.f, p1 = 0.f;
        #pragma unroll
        for (int q = 0; q < 4; ++q) {
            const int e = lane * 16 + q * 4;
            if (e + 3 < 300) {
                float4 w0 = *(const float4*)(W_cls + e);
                float4 w1 = *(const float4*)(W_cls + 300 + e);
                p0 = fmaf(ev[q*4], w0.x, p0); p0 = fmaf(ev[q*4+1], w0.y, p0);
                p0 = fmaf(ev[q*4+2], w0.z, p0); p0 = fmaf(ev[q*4+3], w0.w, p0);
                p1 = fmaf(ev[q*4], w1.x, p1); p1 = fmaf(ev[q*4+1], w1.y, p1);
                p1 = fmaf(ev[q*4+2], w1.z, p1); p1 = fmaf(ev[q*4+3], w1.w, p1);
            } else {
                #pragma unroll
                for (int j = 0; j < 4; ++j) {
                    if (e + j < 300) {
                        p0 = fmaf(ev[q*4+j], W_cls[e + j], p0);
                        p1 = fmaf(ev[q*4+j], W_cls[300 + e + j], p1);
                    }
                }
            }
        }
        p0 = wave_red(p0); p1 = wave_red(p1);
        if (lane == 0) {
            const float l0 = p0 + b_cls[0];
            const float l1 = p1 + b_cls[1];
            const float mx = fmaxf(l0, l1);
            const float lse = mx + logf(expf(l0 - mx) + expf(l1 - mx));
            blk[1] = lse - (labels[row] ? l1 : l0);
        }
    }
    __syncthreads();
    if (threadIdx.x == 0) atomicAdd(&db[blockIdx.x & (NBUCKET - 1)], blk[0]);
    if (threadIdx.x == 1) atomicAdd(&cb[blockIdx.x & (NBUCKET - 1)], blk[1]);
}

// ---------------------------------------------------------------------------
__global__ __launch_bounds__(256)
void finalize_kernel(const float* __restrict__ db, const float* __restrict__ cb,
                     float* __restrict__ out)
{
    const int t = threadIdx.x;
    float d = db[t] + db[t + 256];
    float c = cb[t] + cb[t + 256];
    d = wave_red(d); c = wave_red(c);
    __shared__ float sd[4], sc[4];
    if ((t & 63) == 0) { sd[t >> 6] = d; sc[t >> 6] = c; }
    __syncthreads();
    if (t == 0) {
        const float inv = 1.0f / (float)BATCH;
        float deno = (sd[0] + sd[1] + sd[2] + sd[3]) * inv;
        float cono = (sc[0] + sc[1] + sc[2] + sc[3]) * inv;
        deno = fminf(10.f, fmaxf(EPSV, deno));
        cono = fminf(10.f, fmaxf(EPSV, cono));
        out[0] = fmaxf(EPSV, deno + cono);
        out[1] = deno;
        out[2] = cono;
    }
}

extern "C" void kernel_launch(void* const* d_in, const int* in_sizes, int n_in,
                              void* d_out, int out_size, void* d_ws, size_t ws_size,
                              hipStream_t stream)
{
    const int*   cids  = (const int*)d_in[0];
    const int*   ctx   = (const int*)d_in[1];
    const int*   neg   = (const int*)d_in[2];
    const int*   lab   = (const int*)d_in[3];
    const float* cemb  = (const float*)d_in[4];
    const float* xemb  = (const float*)d_in[5];
    const float* W_enc = (const float*)d_in[6];
    const float* b_enc = (const float*)d_in[7];
    const float* W_dec = (const float*)d_in[8];
    const float* b_dec = (const float*)d_in[9];
    const float* W_cls = (const float*)d_in[10];
    const float* b_cls = (const float*)d_in[11];
    float* out = (float*)d_out;

    // workspace layout (16B aligned): ~92.8 MB total
    unsigned short* emb_b  = (unsigned short*)d_ws;                  // [BATCH][KPAD]
    unsigned short* wenc_b = emb_b  + (size_t)BATCH * KPAD;          // [NPAD][KPAD]
    unsigned short* wdec_b = wenc_b + (size_t)NPAD * KPAD;           // [NPAD][KPAD]
    unsigned short* enc_b  = wdec_b + (size_t)NPAD * KPAD;           // [BATCH][KPAD]
    unsigned short* cv_b   = enc_b  + (size_t)BATCH * KPAD;          // [BATCH][CV_STRIDE]
    unsigned char*  ctx8   = (unsigned char*)(cv_b + (size_t)BATCH * CV_STRIDE);
    float* buckets = (float*)(ctx8 + (size_t)VOCAB * CTX8_STRIDE);   // 2*NBUCKET
    float* db = buckets;
    float* cb = buckets + NBUCKET;

    hipMemsetAsync(buckets, 0, 2 * NBUCKET * sizeof(float), stream);

    const int nprep = (NW + NE + NC + 255) / 256;
    prep_kernel<<<nprep, 256, 0, stream>>>(W_enc, W_dec, cemb, cids, xemb,
                                           wenc_b, wdec_b, emb_b, ctx8);

    dim3 ggrid(3, BATCH / 128);
    mfma_gemm_kernel<KPAD, true><<<ggrid, 256, 0, stream>>>(emb_b, wenc_b, b_enc, enc_b);
    mfma_gemm_kernel<CV_STRIDE, true><<<ggrid, 256, 0, stream>>>(enc_b, wdec_b, b_dec, cv_b);

    score_ce_kernel<<<BATCH, 256, 0, stream>>>(cv_b, enc_b, ctx8, ctx, neg, lab,
                                               W_cls, b_cls, db, cb);
    finalize_kernel<<<1, 256, 0, stream>>>(db, cb, out);
}

// Round 5
// 422.572 us; speedup vs baseline: 1.0088x; 1.0088x over previous
//
#include <hip/hip_runtime.h>
#include <math.h>

#define VOCAB   100000
#define EMBED   300
#define HIDDEN  300
#define BATCH   32768
#define K_NEG   10
#define EPSV    1e-5f

#define KPAD      320        // K padded to multiple of 32 (bf16 MFMA K)
#define NPAD      384        // W2 rows padded to 3*128 N tiles
#define CV_STRIDE 304        // center_v bf16 row stride in shorts (608 B)
#define CTX8_STRIDE 304      // fp8 ctx row stride in BYTES
#define WC2_STRIDE 304       // padded classifier row (f32)
#define FP8_SCALE 64.0f
#define FP8_DESCALE 0.015625f
#define NBUCKET 512

typedef __attribute__((ext_vector_type(8))) short  short8;
typedef __attribute__((ext_vector_type(4))) float  f32x4;
typedef __attribute__((ext_vector_type(2))) float  floatx2;

#if defined(__has_builtin)
#if __has_builtin(__builtin_amdgcn_cvt_pk_f32_fp8) && __has_builtin(__builtin_amdgcn_cvt_pk_fp8_f32)
#define HAVE_CVT_FP8 1
#endif
#endif

__device__ inline float b2f(unsigned short u) {
    union { unsigned int i; float f; } v; v.i = ((unsigned int)u) << 16; return v.f;
}
__device__ inline unsigned short f2b(float f) {
    union { float f; unsigned int i; } v; v.f = f;
    unsigned int r = v.i + 0x7FFFu + ((v.i >> 16) & 1u);   // RNE
    return (unsigned short)(r >> 16);
}
__device__ inline void up2(unsigned int u, float& lo, float& hi) {
    union { unsigned int i; float f; } a, b;
    a.i = u << 16; b.i = u & 0xFFFF0000u;
    lo = a.f; hi = b.f;
}
__device__ inline float softplusf(float x) {
    return x > 0.f ? x + log1pf(expf(-x)) : log1pf(expf(x));
}

// ---- fp8 e4m3 helpers -----------------------------------------------------
__device__ inline float fp8_to_f(unsigned int u8) {
    const unsigned s = (u8 >> 7) & 1, e = (u8 >> 3) & 15, m = u8 & 7;
    float v;
    if (e) { union { unsigned i; float f; } b; b.i = ((e + 120u) << 23) | (m << 20); v = b.f; }
    else v = (float)m * 0.001953125f;
    return s ? -v : v;
}
__device__ inline unsigned char f_to_fp8(float x) {
    union { float f; unsigned i; } b; b.f = x;
    const unsigned s = (b.i >> 31) << 7;
    const float a = fabsf(x);
    if (a >= 440.f) return (unsigned char)(s | 0x7E);
    if (a < 0.015625f) {
        int m = (int)rintf(a * 512.f);
        return (unsigned char)(m >= 8 ? (s | 0x08) : (s | (unsigned)m));
    }
    unsigned r = (b.i & 0x7FFFFFFFu) + 0x7FFFFu + ((b.i >> 20) & 1u);
    unsigned e8 = (r >> 23) - 120u;
    unsigned m8 = (r >> 20) & 7u;
    if (e8 > 15u) return (unsigned char)(s | 0x7E);
    return (unsigned char)(s | (e8 << 3) | m8);
}
__device__ inline unsigned enc4fp8(float a, float b, float c, float d) {
#ifdef HAVE_CVT_FP8
    int v = 0;
    v = __builtin_amdgcn_cvt_pk_fp8_f32(a, b, v, false);
    v = __builtin_amdgcn_cvt_pk_fp8_f32(c, d, v, true);
    return (unsigned)v;
#else
    return (unsigned)f_to_fp8(a) | ((unsigned)f_to_fp8(b) << 8) |
           ((unsigned)f_to_fp8(c) << 16) | ((unsigned)f_to_fp8(d) << 24);
#endif
}
__device__ inline void dec4fp8(unsigned u, float* f) {
#ifdef HAVE_CVT_FP8
    floatx2 lo = __builtin_amdgcn_cvt_pk_f32_fp8((int)u, false);
    floatx2 hi = __builtin_amdgcn_cvt_pk_f32_fp8((int)u, true);
    f[0] = lo[0]; f[1] = lo[1]; f[2] = hi[0]; f[3] = hi[1];
#else
    f[0] = fp8_to_f(u); f[1] = fp8_to_f(u >> 8);
    f[2] = fp8_to_f(u >> 16); f[3] = fp8_to_f(u >> 24);
#endif
}

__device__ inline void load_lds16(const void* g, void* l) {
    __builtin_amdgcn_global_load_lds(
        (const __attribute__((address_space(1))) unsigned int*)g,
        (__attribute__((address_space(3))) unsigned int*)l, 16, 0, 0);
}

// ---------------------------------------------------------------------------
// prep: gather+pack center rows -> bf16 [BATCH][KPAD];
//       pack context_emb -> fp8 e4m3 (x64) [VOCAB][304 B].
// ---------------------------------------------------------------------------
#define NE (BATCH * 40)
#define NC (VOCAB * 19)

__global__ __launch_bounds__(256)
void prep_kernel(const float* __restrict__ cemb, const int* __restrict__ cids,
                 const float* __restrict__ xemb,
                 unsigned short* __restrict__ emb_b, unsigned char* __restrict__ ctx8)
{
    const int gid = blockIdx.x * 256 + threadIdx.x;
    if (gid < NE) {
        const int row = gid / 40;
        const int c8  = (gid - row * 40) * 8;
        const float* src = cemb + (size_t)cids[row] * 300;
        unsigned short t[8];
        if (c8 + 7 < 300) {
            float4 a = *(const float4*)(src + c8);
            float4 b = *(const float4*)(src + c8 + 4);
            t[0]=f2b(a.x); t[1]=f2b(a.y); t[2]=f2b(a.z); t[3]=f2b(a.w);
            t[4]=f2b(b.x); t[5]=f2b(b.y); t[6]=f2b(b.z); t[7]=f2b(b.w);
        } else {
            #pragma unroll
            for (int j = 0; j < 8; ++j) {
                const int c = c8 + j;
                t[j] = (c < 300) ? f2b(src[c]) : (unsigned short)0;
            }
        }
        *(uint4*)(emb_b + (size_t)row * KPAD + c8) = *(const uint4*)t;
    } else if (gid < NE + NC) {
        const int g3  = gid - NE;
        const int row = g3 / 19;
        const int l   = g3 - row * 19;
        const int e0  = l * 16;
        const float* src = xemb + (size_t)row * 300 + e0;
        float v[16];
        #pragma unroll
        for (int q = 0; q < 4; ++q) {
            if (e0 + q * 4 + 3 < 300) {
                float4 a = *(const float4*)(src + q * 4);
                v[q*4+0]=a.x; v[q*4+1]=a.y; v[q*4+2]=a.z; v[q*4+3]=a.w;
            } else {
                #pragma unroll
                for (int j = 0; j < 4; ++j) {
                    const int e = e0 + q * 4 + j;
                    v[q*4+j] = (e < 300) ? src[q*4+j] : 0.f;
                }
            }
        }
        unsigned u[4];
        #pragma unroll
        for (int q = 0; q < 4; ++q)
            u[q] = enc4fp8(v[q*4]*FP8_SCALE, v[q*4+1]*FP8_SCALE,
                           v[q*4+2]*FP8_SCALE, v[q*4+3]*FP8_SCALE);
        *(uint4*)(ctx8 + (size_t)row * CTX8_STRIDE + e0) = make_uint4(u[0],u[1],u[2],u[3]);
    }
}

// ---------------------------------------------------------------------------
// W2 = W_dec @ W_enc  [300x300] f32 -> bf16 packed [NPAD][KPAD], zero padded.
// w2p[n][k] = sum_h W_dec[n][h] * W_enc[h][k]
// 16x16 output tile per block, BH=32 K-chunks via LDS.
// ---------------------------------------------------------------------------
__global__ __launch_bounds__(256)
void w2_kernel(const float* __restrict__ Wd, const float* __restrict__ We,
               unsigned short* __restrict__ w2p)
{
    __shared__ float ds[16][33];
    __shared__ float es[32][17];
    const int tid = threadIdx.x;
    const int tn = tid >> 4, tk = tid & 15;
    const int n = blockIdx.y * 16 + tn;
    const int k = blockIdx.x * 16 + tk;

    float acc = 0.f;
    for (int h0 = 0; h0 < 300; h0 += 32) {
        // load Wd tile [16][32]
        {
            const int i = tid * 2;
            const int a = i >> 5, h = i & 31;
            const int rr = blockIdx.y * 16 + a;
            #pragma unroll
            for (int j = 0; j < 2; ++j) {
                const int hh = h + j;
                ds[a][hh] = (rr < 300 && h0 + hh < 300) ? Wd[rr * 300 + h0 + hh] : 0.f;
            }
        }
        // load We tile [32][16]
        {
            const int i = tid * 2;
            const int h = i >> 4, c = i & 15;   // c in {0,2,4,...}? no: i&15 with step2
            const int cc = blockIdx.x * 16 + c;
            #pragma unroll
            for (int j = 0; j < 2; ++j)
                es[h][c + j] = (h0 + h < 300 && cc + j < 300) ? We[(h0 + h) * 300 + cc + j] : 0.f;
        }
        __syncthreads();
        #pragma unroll
        for (int h = 0; h < 32; ++h)
            acc = fmaf(ds[tn][h], es[h][tk], acc);
        __syncthreads();
    }
    if (n < NPAD && k < KPAD)
        w2p[n * KPAD + k] = (n < 300 && k < 300) ? f2b(acc) : (unsigned short)0;
}

// ---------------------------------------------------------------------------
// wb: bias2[c] = W_dec[c,:]·b_enc + b_dec[c];  wc2[j][c] = sum_h W_cls[j][h]·W_enc[h][c]
//     bc2[j] = W_cls[j,:]·b_enc + b_cls[j].  One block, 320 threads.
// ---------------------------------------------------------------------------
__global__ __launch_bounds__(320)
void wb_kernel(const float* __restrict__ Wd, const float* __restrict__ We,
               const float* __restrict__ Wc, const float* __restrict__ b_enc,
               const float* __restrict__ b_dec, const float* __restrict__ b_cls,
               float* __restrict__ wc2, float* __restrict__ bias2, float* __restrict__ bc2)
{
    const int c = threadIdx.x;
    if (c < WC2_STRIDE) {
        float b2 = 0.f, a0 = 0.f, a1 = 0.f;
        if (c < 300) {
            for (int k = 0; k < 300; ++k) b2 = fmaf(Wd[c * 300 + k], b_enc[k], b2);
            for (int h = 0; h < 300; ++h) {
                const float we = We[h * 300 + c];
                a0 = fmaf(Wc[h], we, a0);
                a1 = fmaf(Wc[300 + h], we, a1);
            }
            b2 += b_dec[c];
        }
        bias2[c] = b2;
        wc2[c] = a0;
        wc2[WC2_STRIDE + c] = a1;
    } else if (c < WC2_STRIDE + 2) {
        const int j = c - WC2_STRIDE;
        float s = 0.f;
        for (int h = 0; h < 300; ++h) s = fmaf(Wc[j * 300 + h], b_enc[h], s);
        bc2[j] = s + b_cls[j];
    }
}

// ---------------------------------------------------------------------------
// MFMA bf16 GEMM, double-buffered LDS via global_load_lds, one barrier/iter.
// cv[m,n] = sum_k emb[m,k]*W2[n,k] + bias2[n]; out bf16 stride CV_STRIDE,
// cols [300,304) zeroed.
// ---------------------------------------------------------------------------
__global__ __launch_bounds__(256)
void gemm_cv_kernel(const unsigned short* __restrict__ A,
                    const unsigned short* __restrict__ B,
                    const float* __restrict__ bias,
                    unsigned short* __restrict__ C)
{
    __shared__ unsigned short As[2][128 * 32];
    __shared__ unsigned short Bs[2][128 * 32];

    const int tid  = threadIdx.x;
    const int wave = tid >> 6;
    const int lane = tid & 63;
    const int m0 = blockIdx.y * 128;
    const int n0 = blockIdx.x * 128;

    const int wr = (wave & 1) * 64;
    const int wc = (wave >> 1) * 64;
    const int fr = lane & 15;
    const int fq = lane >> 4;

    const unsigned short* gA[2];
    const unsigned short* gB[2];
    int ldsOff[2];
    #pragma unroll
    for (int inst = 0; inst < 2; ++inst) {
        const int t = wave * 2 + inst;
        const int r = (t << 4) + (lane >> 2);
        const int c = ((lane & 3) - r - (r >> 2)) & 3;
        gA[inst] = A + (size_t)(m0 + r) * KPAD + c * 8;
        gB[inst] = B + (size_t)(n0 + r) * KPAD + c * 8;
        ldsOff[inst] = t << 9;
    }

    int aoff[4], boff[4];
    #pragma unroll
    for (int i = 0; i < 4; ++i) {
        const int ra = wr + i * 16 + fr;
        aoff[i] = (ra << 5) + (((fq + ra + (ra >> 2)) & 3) << 3);
        const int rb = wc + i * 16 + fr;
        boff[i] = (rb << 5) + (((fq + rb + (rb >> 2)) & 3) << 3);
    }

    f32x4 acc[4][4] = {};

    // prologue: stage chunk 0 into buffer 0
    #pragma unroll
    for (int inst = 0; inst < 2; ++inst) {
        load_lds16(gA[inst], &As[0][ldsOff[inst]]);
        load_lds16(gB[inst], &Bs[0][ldsOff[inst]]);
    }

    int cur = 0;
    for (int ki = 0; ki < KPAD / 32; ++ki) {
        __syncthreads();                 // chunk ki resident; prev reads done
        if (ki + 1 < KPAD / 32) {        // prefetch next into other buffer
            const int k0 = (ki + 1) * 32;
            #pragma unroll
            for (int inst = 0; inst < 2; ++inst) {
                load_lds16(gA[inst] + k0, &As[cur ^ 1][ldsOff[inst]]);
                load_lds16(gB[inst] + k0, &Bs[cur ^ 1][ldsOff[inst]]);
            }
        }
        short8 af[4], bf[4];
        #pragma unroll
        for (int i = 0; i < 4; ++i) af[i] = *(const short8*)&As[cur][aoff[i]];
        #pragma unroll
        for (int j = 0; j < 4; ++j) bf[j] = *(const short8*)&Bs[cur][boff[j]];
        #pragma unroll
        for (int i = 0; i < 4; ++i)
            #pragma unroll
            for (int j = 0; j < 4; ++j)
                acc[i][j] = __builtin_amdgcn_mfma_f32_16x16x32_bf16(
                    af[i], bf[j], acc[i][j], 0, 0, 0);
        cur ^= 1;
    }

    #pragma unroll
    for (int i = 0; i < 4; ++i) {
        #pragma unroll
        for (int r = 0; r < 4; ++r) {
            const int m = m0 + wr + i * 16 + fq * 4 + r;
            unsigned short* crow = C + (size_t)m * CV_STRIDE;
            #pragma unroll
            for (int j = 0; j < 4; ++j) {
                const int n = n0 + wc + j * 16 + fr;
                if (n < 300) {
                    crow[n] = f2b(acc[i][j][r] + bias[n]);
                } else if (n < CV_STRIDE) {
                    crow[n] = 0;
                }
            }
        }
    }
}

// ---------------------------------------------------------------------------
// score: each wave = 2 units in 32-lane halves. unit -> (row, g); group g
// covers scores t = g*4-1+j for j=0..3 (t=-1 => positive ctx; t<=9 included).
// ---------------------------------------------------------------------------
__global__ __launch_bounds__(256)
void score_kernel(const unsigned short* __restrict__ cvb,
                  const unsigned char* __restrict__ ctx8,
                  const int* __restrict__ ctx_ids, const int* __restrict__ neg_ids,
                  float* __restrict__ db)
{
    const int wid  = threadIdx.x >> 6;
    const int lane = threadIdx.x & 63;
    const int l5   = lane & 31;
    const int unit = blockIdx.x * 8 + wid * 2 + (lane >> 5);
    const int row  = unit / 3;
    const int g    = unit - row * 3;
    const bool act = l5 < 19;

    const int b = row * K_NEG;
    int ids[4]; bool inc[4]; bool pos[4];
    #pragma unroll
    for (int j = 0; j < 4; ++j) {
        const int t = g * 4 - 1 + j;
        pos[j] = (t < 0);
        inc[j] = (t <= 9);
        ids[j] = pos[j] ? ctx_ids[row] : neg_ids[b + (t > 9 ? 9 : t)];
    }

    const uint4 Z4 = make_uint4(0, 0, 0, 0);
    const char* cvp = (const char*)(cvb + (size_t)row * CV_STRIDE);
    uint4 c0 = act ? *(const uint4*)(cvp + l5 * 32)      : Z4;
    uint4 c1 = act ? *(const uint4*)(cvp + l5 * 32 + 16) : Z4;

    uint4 gv[4];
    #pragma unroll
    for (int j = 0; j < 4; ++j)
        gv[j] = act ? *(const uint4*)(ctx8 + (size_t)ids[j] * CTX8_STRIDE + l5 * 16) : Z4;

    float cvf[16];
    up2(c0.x, cvf[0], cvf[1]);  up2(c0.y, cvf[2], cvf[3]);
    up2(c0.z, cvf[4], cvf[5]);  up2(c0.w, cvf[6], cvf[7]);
    up2(c1.x, cvf[8], cvf[9]);  up2(c1.y, cvf[10], cvf[11]);
    up2(c1.z, cvf[12], cvf[13]);up2(c1.w, cvf[14], cvf[15]);

    float ds[4];
    #pragma unroll
    for (int j = 0; j < 4; ++j) {
        float gf[16];
        dec4fp8(gv[j].x, gf); dec4fp8(gv[j].y, gf + 4);
        dec4fp8(gv[j].z, gf + 8); dec4fp8(gv[j].w, gf + 12);
        float s = 0.f;
        #pragma unroll
        for (int e = 0; e < 16; ++e) s = fmaf(cvf[e], gf[e], s);
        ds[j] = s;
    }
    // xor-shuffle reduction within each 32-lane half
    #pragma unroll
    for (int j = 0; j < 4; ++j) {
        float v = ds[j];
        #pragma unroll
        for (int m = 16; m; m >>= 1) v += __shfl_xor(v, m);
        ds[j] = v;
    }

    if (l5 == 0) {
        float local = 0.f;
        #pragma unroll
        for (int j = 0; j < 4; ++j) {
            if (inc[j]) {
                float s = fminf(10.f, fmaxf(-10.f, ds[j] * FP8_DESCALE));
                local += softplusf(pos[j] ? -s : s);
            }
        }
        atomicAdd(&db[blockIdx.x & (NBUCKET - 1)], local);
    }
}

// ---------------------------------------------------------------------------
// CE: each wave = 2 rows in 32-lane halves; logits = emb_row·wc2[j] + bc2[j].
// ---------------------------------------------------------------------------
__global__ __launch_bounds__(256)
void ce_kernel(const unsigned short* __restrict__ embb,
               const int* __restrict__ labels,
               const float* __restrict__ wc2, const float* __restrict__ bc2,
               float* __restrict__ cb)
{
    const int wid  = threadIdx.x >> 6;
    const int lane = threadIdx.x & 63;
    const int l5   = lane & 31;
    const int row  = blockIdx.x * 8 + wid * 2 + (lane >> 5);
    const bool act = l5 < 19;

    const uint4 Z4 = make_uint4(0, 0, 0, 0);
    const char* evp = (const char*)(embb + (size_t)row * KPAD);
    uint4 e0 = act ? *(const uint4*)(evp + l5 * 32)      : Z4;
    uint4 e1 = act ? *(const uint4*)(evp + l5 * 32 + 16) : Z4;
    float ev[16];
    up2(e0.x, ev[0], ev[1]);  up2(e0.y, ev[2], ev[3]);
    up2(e0.z, ev[4], ev[5]);  up2(e0.w, ev[6], ev[7]);
    up2(e1.x, ev[8], ev[9]);  up2(e1.y, ev[10], ev[11]);
    up2(e1.z, ev[12], ev[13]);up2(e1.w, ev[14], ev[15]);

    float p0 = 0.f, p1 = 0.f;
    if (act) {
        const float* w0 = wc2 + l5 * 16;
        const float* w1 = wc2 + WC2_STRIDE + l5 * 16;
        #pragma unroll
        for (int q = 0; q < 4; ++q) {
            float4 a = *(const float4*)(w0 + q * 4);
            float4 c = *(const float4*)(w1 + q * 4);
            p0 = fmaf(ev[q*4], a.x, p0); p0 = fmaf(ev[q*4+1], a.y, p0);
            p0 = fmaf(ev[q*4+2], a.z, p0); p0 = fmaf(ev[q*4+3], a.w, p0);
            p1 = fmaf(ev[q*4], c.x, p1); p1 = fmaf(ev[q*4+1], c.y, p1);
            p1 = fmaf(ev[q*4+2], c.z, p1); p1 = fmaf(ev[q*4+3], c.w, p1);
        }
    }
    #pragma unroll
    for (int m = 16; m; m >>= 1) { p0 += __shfl_xor(p0, m); p1 += __shfl_xor(p1, m); }

    if (l5 == 0) {
        const float l0 = p0 + bc2[0];
        const float l1 = p1 + bc2[1];
        const float mx = fmaxf(l0, l1);
        const float lse = mx + logf(expf(l0 - mx) + expf(l1 - mx));
        const float nll = lse - (labels[row] ? l1 : l0);
        atomicAdd(&cb[blockIdx.x & (NBUCKET - 1)], nll);
    }
}

// ---------------------------------------------------------------------------
__device__ inline float wave_red64(float v) {
    #pragma unroll
    for (int o = 32; o; o >>= 1) v += __shfl_down(v, o);
    return v;
}
__global__ __launch_bounds__(256)
void finalize_kernel(const float* __restrict__ db, const float* __restrict__ cb,
                     float* __restrict__ out)
{
    const int t = threadIdx.x;
    float d = db[t] + db[t + 256];
    float c = cb[t] + cb[t + 256];
    d = wave_red64(d); c = wave_red64(c);
    __shared__ float sd[4], sc[4];
    if ((t & 63) == 0) { sd[t >> 6] = d; sc[t >> 6] = c; }
    __syncthreads();
    if (t == 0) {
        const float inv = 1.0f / (float)BATCH;
        float deno = (sd[0] + sd[1] + sd[2] + sd[3]) * inv;
        float cono = (sc[0] + sc[1] + sc[2] + sc[3]) * inv;
        deno = fminf(10.f, fmaxf(EPSV, deno));
        cono = fminf(10.f, fmaxf(EPSV, cono));
        out[0] = fmaxf(EPSV, deno + cono);
        out[1] = deno;
        out[2] = cono;
    }
}

extern "C" void kernel_launch(void* const* d_in, const int* in_sizes, int n_in,
                              void* d_out, int out_size, void* d_ws, size_t ws_size,
                              hipStream_t stream)
{
    const int*   cids  = (const int*)d_in[0];
    const int*   ctx   = (const int*)d_in[1];
    const int*   neg   = (const int*)d_in[2];
    const int*   lab   = (const int*)d_in[3];
    const float* cemb  = (const float*)d_in[4];
    const float* xemb  = (const float*)d_in[5];
    const float* W_enc = (const float*)d_in[6];
    const float* b_enc = (const float*)d_in[7];
    const float* W_dec = (const float*)d_in[8];
    const float* b_dec = (const float*)d_in[9];
    const float* W_cls = (const float*)d_in[10];
    const float* b_cls = (const float*)d_in[11];
    float* out = (float*)d_out;

    // workspace (~71.6 MB, all 16B aligned)
    unsigned short* emb_b = (unsigned short*)d_ws;                   // [BATCH][KPAD]
    unsigned short* cv_b  = emb_b + (size_t)BATCH * KPAD;            // [BATCH][CV_STRIDE]
    unsigned char*  ctx8  = (unsigned char*)(cv_b + (size_t)BATCH * CV_STRIDE);
    unsigned short* w2p   = (unsigned short*)(ctx8 + (size_t)VOCAB * CTX8_STRIDE);
    float* wc2   = (float*)(w2p + (size_t)NPAD * KPAD);              // [2][WC2_STRIDE]
    float* bias2 = wc2 + 2 * WC2_STRIDE;                             // [WC2_STRIDE]
    float* bc2   = bias2 + WC2_STRIDE;                               // [2] (+pad)
    float* db    = bc2 + 4;                                          // [NBUCKET]
    float* cb    = db + NBUCKET;                                     // [NBUCKET]

    hipMemsetAsync(db, 0, 2 * NBUCKET * sizeof(float), stream);

    prep_kernel<<<(NE + NC + 255) / 256, 256, 0, stream>>>(cemb, cids, xemb, emb_b, ctx8);

    dim3 wgrid(KPAD / 16, NPAD / 16);
    w2_kernel<<<wgrid, 256, 0, stream>>>(W_dec, W_enc, w2p);
    wb_kernel<<<1, 320, 0, stream>>>(W_dec, W_enc, W_cls, b_enc, b_dec, b_cls,
                                     wc2, bias2, bc2);

    dim3 ggrid(3, BATCH / 128);
    gemm_cv_kernel<<<ggrid, 256, 0, stream>>>(emb_b, w2p, bias2, cv_b);

    score_kernel<<<3 * BATCH / 8, 256, 0, stream>>>(cv_b, ctx8, ctx, neg, db);
    ce_kernel<<<BATCH / 8, 256, 0, stream>>>(emb_b, lab, wc2, bc2, cb);

    finalize_kernel<<<1, 256, 0, stream>>>(db, cb, out);
}